// Round 1
// baseline (80.304 us; speedup 1.0000x reference)
//
#include <hip/hip_runtime.h>
#include <math.h>

constexpr int NQ  = 12;
constexpr int NS  = 1 << NQ;   // 4096 amplitudes
constexpr int NL  = 4;
constexpr int BLK = 512;       // 8 waves/block -> 2 waves/SIMD (was 4 waves -> 1/SIMD)
constexpr int R   = 8;         // amplitudes per thread (reg bits = amp bits 0..2)
constexpr float PI_F = 3.14159265358979323846f;

// amp index i = (tid << 3) | r
//   bits 0..2  : register index r
//   bits 3..8  : lane bits (tid bits 0..5)
//   bits 9..11 : wave bits (tid bits 6..8)
// wire q <-> amp bit (11-q):
//   wire0->tid b8, wire1->tid b7, wire2->tid b6, wires 3..8 -> lane bits 5..0,
//   wire9->r b2, wire10->r b1, wire11->r b0

typedef float c32 __attribute__((ext_vector_type(2)));   // (re, im) -> v_pk_* math

__device__ __forceinline__ c32 cmul(c32 a, c32 b) {
    c32 t = (c32){-a.y, a.y} * b.yx;
    return (c32){a.x, a.x} * b + t;
}
struct cg { c32 xx, ny; };
__device__ __forceinline__ cg mkg(c32 u) {
    cg g; g.xx = (c32){u.x, u.x}; g.ny = (c32){-u.y, u.y}; return g;
}
__device__ __forceinline__ c32 cmulg(cg g, c32 b) { return g.xx * b + g.ny * b.yx; }
__device__ __forceinline__ c32 cmadg(cg g, c32 b, c32 c) { return g.xx * b + (g.ny * b.yx + c); }

// hard scheduling fence: nothing moves across (forces the whole exchange
// batch live before any consumer -> wide ILP window, no chain serialization)
__device__ __forceinline__ void sfence() { __builtin_amdgcn_sched_barrier(0); }

// ---------------- VALU lane-exchange primitives ----------------
template<int CTRL>
__device__ __forceinline__ float dppmov(float v) {
    return __int_as_float(__builtin_amdgcn_mov_dpp(__float_as_int(v), CTRL, 0xF, 0xF, false));
}
__device__ __forceinline__ float dppx4(float v) {
    int s = __float_as_int(v);
    int o = __builtin_amdgcn_update_dpp(s, s, 0x104, 0xF, 0x5, false); // row_shl:4 -> banks 0,2
    o     = __builtin_amdgcn_update_dpp(o, s, 0x114, 0xF, 0xA, false); // row_shr:4 -> banks 1,3
    return __int_as_float(o);
}

#if __has_builtin(__builtin_amdgcn_permlane16_swap)
#define HAVE_PL16 1
#endif
#if __has_builtin(__builtin_amdgcn_permlane32_swap)
#define HAVE_PL32 1
#endif

template<int M>
__device__ __forceinline__ float lanex(float v, int tid) {
    if constexpr (M == 1)  return dppmov<0xB1>(v);        // quad_perm [1,0,3,2]
    else if constexpr (M == 2)  return dppmov<0x4E>(v);   // quad_perm [2,3,0,1]
    else if constexpr (M == 4)  return dppx4(v);
    else if constexpr (M == 8)  return dppmov<0x128>(v);  // row_ror:8
    else if constexpr (M == 16) {
#ifdef HAVE_PL16
        auto r = __builtin_amdgcn_permlane16_swap(__float_as_int(v), __float_as_int(v), false, false);
        return __int_as_float((tid & 16) ? r[0] : r[1]);
#else
        return __shfl_xor(v, 16, 64);
#endif
    } else { // M == 32
#ifdef HAVE_PL32
        auto r = __builtin_amdgcn_permlane32_swap(__float_as_int(v), __float_as_int(v), false, false);
        return __int_as_float((tid & 32) ? r[0] : r[1]);
#else
        return __shfl_xor(v, 32, 64);
#endif
    }
}
template<int M>
__device__ __forceinline__ c32 cx(c32 v, int tid) {
    return (c32){lanex<M>(v.x, tid), lanex<M>(v.y, tid)};
}

template<int P>
__device__ __forceinline__ void gate_reg(c32* v, const c32* u) {
    const cg g00 = mkg(u[0]), g01 = mkg(u[1]), g10 = mkg(u[2]), g11 = mkg(u[3]);
    #pragma unroll
    for (int r = 0; r < R; ++r)
        if (!(r & (1 << P))) {
            c32 a = v[r], b = v[r | (1 << P)];
            v[r]            = cmadg(g01, b, cmulg(g00, a));
            v[r | (1 << P)] = cmadg(g11, b, cmulg(g10, a));
        }
}

// phase-split lane gate with a hard sched fence between phases
template<int M>
__device__ __forceinline__ void gate_lane(c32* v, int tid, const c32* u) {
    const bool hi = tid & M;
    const c32 Ud = hi ? u[3] : u[0];
    const c32 Uo = hi ? u[2] : u[1];
    const cg gd = mkg(Ud), go = mkg(Uo);
    c32 o[R];
    #pragma unroll
    for (int r = 0; r < R; ++r) o[r] = cx<M>(v[r], tid);
    sfence();
    #pragma unroll
    for (int r = 0; r < R; ++r) v[r] = cmadg(gd, v[r], cmulg(go, o[r]));
}

// exec-masked CNOT, phase-split + fence.
template<int CM, int TM>
__device__ __forceinline__ void cnot_ll(c32* v, int tid) {
    if (tid & CM) {
        c32 o[R];
        #pragma unroll
        for (int r = 0; r < R; ++r) o[r] = cx<TM>(v[r], tid);
        sfence();
        #pragma unroll
        for (int r = 0; r < R; ++r) v[r] = o[r];
    }
}

template<int PC, int PT>
__device__ __forceinline__ void cnot_rr(c32* v) {
    #pragma unroll
    for (int r = 0; r < R; ++r)
        if ((r & (1 << PC)) && !(r & (1 << PT))) {
            c32 t = v[r]; v[r] = v[r ^ (1 << PT)]; v[r ^ (1 << PT)] = t;
        }
}

__global__ __launch_bounds__(BLK, 2)
void qsim_kernel(const float* __restrict__ x,    // (B,12)
                 const float* __restrict__ w,    // (4,12,3)
                 const float* __restrict__ ent,  // (4,12)
                 float* __restrict__ out)        // (B,12)
{
    __shared__ c32  xbuf[NS];           // 32 KB cross-wave exchange
    __shared__ c32  gmat[NL * NQ][4];
    __shared__ c32  uenc[NQ][2];
    __shared__ int  entf[NL * NQ];
    __shared__ float redbuf[8 * NQ];

    const int tid = threadIdx.x;
    const int b   = blockIdx.x;

    if (tid < NL * NQ) {
        float phi = w[tid * 3 + 0], th = w[tid * 3 + 1], om = w[tid * 3 + 2];
        float s, c;   sincosf(0.5f * th, &s, &c);
        float sa, ca; sincosf(0.5f * (phi + om), &sa, &ca);
        float sm, cm; sincosf(0.5f * (phi - om), &sm, &cm);
        gmat[tid][0] = (c32){ c * ca, -c * sa};
        gmat[tid][1] = (c32){-s * cm, -s * sm};
        gmat[tid][2] = (c32){ s * cm, -s * sm};
        gmat[tid][3] = (c32){ c * ca,  c * sa};
        entf[tid] = ent[tid] > 0.5f;
    }
    if (tid >= 64 && tid < 64 + NQ) {
        int q = tid - 64;
        float xv = x[b * NQ + q];
        float s, c;   sincosf(0.5f * PI_F * xv, &s, &c);
        float zs, zc; sincosf(0.5f * PI_F * xv * xv, &zs, &zc);
        uenc[q][0] = (c32){c * zc, -c * zs};
        uenc[q][1] = (c32){s * zc,  s * zs};
    }
    __syncthreads();

    // ---- build encoded product state directly in registers ----
    // wires 0..8 come from tid bits 8..0; wires 9..11 from r bits 2..0
    c32 A = uenc[0][(tid >> 8) & 1];
    #pragma unroll
    for (int q = 1; q < 9; ++q) A = cmul(A, uenc[q][(tid >> (8 - q)) & 1]);
    c32 PB[R];
    #pragma unroll
    for (int k = 0; k < R; ++k)
        PB[k] = cmul(uenc[9][(k >> 2) & 1], cmul(uenc[10][(k >> 1) & 1], uenc[11][k & 1]));
    c32 v[R];
    #pragma unroll
    for (int r = 0; r < R; ++r) v[r] = cmul(A, PB[r]);

    const int lane_slot = tid & 63;
    const int g         = tid >> 6;   // 3 bits: amp bits (11,10,9)

    // ---- layers ----
    #pragma unroll 1
    for (int layer = 0; layer < NL; ++layer) {
        const int gb = layer * NQ;

        // ===== fused 8x8 gate on amp bits (11,10,9) =====
        //   = Rot(w0) ⊗ Rot(w1) ⊗ Rot(w2)
        //   + this layer's CNOT(b11,b10) and CNOT(b10,b9) as row perms
        //     (both commute with the later Rots on bits 8..0)
        //   + prev layer's CNOT(b0,b11) as col perm on odd-r amplitudes.
        {
            #pragma unroll
            for (int r = 0; r < R; ++r) xbuf[r * BLK + tid] = v[r];

            const c32* Ua = gmat[gb + 0];
            const c32* Ub = gmat[gb + 1];
            const c32* Uc = gmat[gb + 2];
            // row perm: apply sigma(CNOT b10->b9) first, then sigma(CNOT b11->b10)
            int gp = (entf[gb + 1] && (g & 2)) ? (g ^ 1) : g;
            gp     = (entf[gb + 0] && (gp & 4)) ? (gp ^ 2) : gp;
            const int ar = (gp >> 2) * 2;
            const int br = ((gp >> 1) & 1) * 2;
            const int cr = (gp & 1) * 2;
            // coefficient for partner offset m (column j = g^m)
            cg gE[8];
            #pragma unroll
            for (int m = 0; m < 8; ++m) {
                const int j = g ^ m;
                c32 kk = cmul(Ua[ar + (j >> 2)],
                          cmul(Ub[br + ((j >> 1) & 1)], Uc[cr + (j & 1)]));
                gE[m] = mkg(kk);
            }
            const bool pf = (layer > 0) && entf[gb - 1];   // prev CNOT(b0,b11) fold

            const c32* px = xbuf + lane_slot;

            __syncthreads();
            // --- phase A: r = 0..3 ---
            {
                c32 bm[7][4];
                #pragma unroll
                for (int m = 1; m < 8; ++m) {
                    const c32* pp = px + ((g ^ m) << 6);
                    #pragma unroll
                    for (int r = 0; r < 4; ++r) bm[m - 1][r] = pp[r * BLK];
                }
                sfence();
                #pragma unroll
                for (int r = 0; r < 4; ++r) {
                    c32 acc;
                    if (!(r & 1)) {
                        acc = cmulg(gE[0], v[r]);
                        acc = cmadg(gE[1], bm[0][r], acc);
                        acc = cmadg(gE[2], bm[1][r], acc);
                        acc = cmadg(gE[3], bm[2][r], acc);
                        acc = cmadg(gE[4], bm[3][r], acc);
                        acc = cmadg(gE[5], bm[4][r], acc);
                        acc = cmadg(gE[6], bm[5][r], acc);
                        acc = cmadg(gE[7], bm[6][r], acc);
                    } else if (!pf) {
                        acc = cmulg(gE[0], v[r]);
                        acc = cmadg(gE[1], bm[0][r], acc);
                        acc = cmadg(gE[2], bm[1][r], acc);
                        acc = cmadg(gE[3], bm[2][r], acc);
                        acc = cmadg(gE[4], bm[3][r], acc);
                        acc = cmadg(gE[5], bm[4][r], acc);
                        acc = cmadg(gE[6], bm[5][r], acc);
                        acc = cmadg(gE[7], bm[6][r], acc);
                    } else {  // odd r, col perm: coefficient index m^4
                        acc = cmulg(gE[4], v[r]);
                        acc = cmadg(gE[5], bm[0][r], acc);
                        acc = cmadg(gE[6], bm[1][r], acc);
                        acc = cmadg(gE[7], bm[2][r], acc);
                        acc = cmadg(gE[0], bm[3][r], acc);
                        acc = cmadg(gE[1], bm[4][r], acc);
                        acc = cmadg(gE[2], bm[5][r], acc);
                        acc = cmadg(gE[3], bm[6][r], acc);
                    }
                    v[r] = acc;
                }
            }
            // --- phase B: r = 4..7 ---
            {
                c32 bm[7][4];
                #pragma unroll
                for (int m = 1; m < 8; ++m) {
                    const c32* pp = px + ((g ^ m) << 6) + 4 * BLK;
                    #pragma unroll
                    for (int r = 0; r < 4; ++r) bm[m - 1][r] = pp[r * BLK];
                }
                sfence();
                #pragma unroll
                for (int rr = 0; rr < 4; ++rr) {
                    const int r = rr + 4;
                    c32 acc;
                    if (!(r & 1)) {
                        acc = cmulg(gE[0], v[r]);
                        acc = cmadg(gE[1], bm[0][rr], acc);
                        acc = cmadg(gE[2], bm[1][rr], acc);
                        acc = cmadg(gE[3], bm[2][rr], acc);
                        acc = cmadg(gE[4], bm[3][rr], acc);
                        acc = cmadg(gE[5], bm[4][rr], acc);
                        acc = cmadg(gE[6], bm[5][rr], acc);
                        acc = cmadg(gE[7], bm[6][rr], acc);
                    } else if (!pf) {
                        acc = cmulg(gE[0], v[r]);
                        acc = cmadg(gE[1], bm[0][rr], acc);
                        acc = cmadg(gE[2], bm[1][rr], acc);
                        acc = cmadg(gE[3], bm[2][rr], acc);
                        acc = cmadg(gE[4], bm[3][rr], acc);
                        acc = cmadg(gE[5], bm[4][rr], acc);
                        acc = cmadg(gE[6], bm[5][rr], acc);
                        acc = cmadg(gE[7], bm[6][rr], acc);
                    } else {
                        acc = cmulg(gE[4], v[r]);
                        acc = cmadg(gE[5], bm[0][rr], acc);
                        acc = cmadg(gE[6], bm[1][rr], acc);
                        acc = cmadg(gE[7], bm[2][rr], acc);
                        acc = cmadg(gE[0], bm[3][rr], acc);
                        acc = cmadg(gE[1], bm[4][rr], acc);
                        acc = cmadg(gE[2], bm[5][rr], acc);
                        acc = cmadg(gE[3], bm[6][rr], acc);
                    }
                    v[r] = acc;
                }
            }
            __syncthreads();
        }

        // ===== Rot gates on lane bits and reg bits =====
        gate_lane<32>(v, tid, gmat[gb + 3]);   // wire3 / bit8
        gate_lane<16>(v, tid, gmat[gb + 4]);   // wire4 / bit7
        gate_lane< 8>(v, tid, gmat[gb + 5]);   // wire5 / bit6
        gate_lane< 4>(v, tid, gmat[gb + 6]);   // wire6 / bit5
        gate_lane< 2>(v, tid, gmat[gb + 7]);   // wire7 / bit4
        gate_lane< 1>(v, tid, gmat[gb + 8]);   // wire8 / bit3
        gate_reg<2>(v, gmat[gb + 9]);          // wire9 / bit2
        gate_reg<1>(v, gmat[gb + 10]);         // wire10 / bit1
        gate_reg<0>(v, gmat[gb + 11]);         // wire11 / bit0

        // ===== CNOT chain =====
        // (w0,w1),(w1,w2) folded into fused gate; (w11,w0) folded forward
        if (entf[gb + 2] && (tid & 64)) {      // (b9,b8): ctrl wave bit6, tgt lane bit5
            c32 o[R];
            #pragma unroll
            for (int r = 0; r < R; ++r) o[r] = cx<32>(v[r], tid);
            sfence();
            #pragma unroll
            for (int r = 0; r < R; ++r) v[r] = o[r];
        }
        if (entf[gb + 3]) cnot_ll<32, 16>(v, tid);   // (b8,b7)
        if (entf[gb + 4]) cnot_ll<16,  8>(v, tid);   // (b7,b6)
        if (entf[gb + 5]) cnot_ll< 8,  4>(v, tid);   // (b6,b5)
        if (entf[gb + 6]) cnot_ll< 4,  2>(v, tid);   // (b5,b4)
        if (entf[gb + 7]) cnot_ll< 2,  1>(v, tid);   // (b4,b3)
        if (entf[gb + 8]) {                          // (b3,b2): ctrl lane bit0, tgt reg bit2
            const bool c_ = tid & 1;
            #pragma unroll
            for (int r = 0; r < 4; ++r) {
                c32 a = v[r], bb = v[r | 4];
                v[r]     = c_ ? bb : a;
                v[r | 4] = c_ ? a  : bb;
            }
        }
        if (entf[gb + 9])  cnot_rr<2, 1>(v);         // (b2,b1)
        if (entf[gb + 10]) cnot_rr<1, 0>(v);         // (b1,b0)
        // (b0,b11): folded into next fused gate, or into measurement
    }

    // ---- measurement; last layer's CNOT(b0,b11) folded into wire0's sign ----
    const bool e011L = entf[(NL - 1) * NQ + 11];
    const int  t8    = (tid >> 8) & 1;

    float pr[R];
    #pragma unroll
    for (int r = 0; r < R; ++r) {
        c32 p = v[r] * v[r];
        pr[r] = p.x + p.y;
    }
    float S = 0.f, acc0 = 0.f;
    #pragma unroll
    for (int r = 0; r < R; ++r) {
        S += pr[r];
        const int s11 = t8 ^ (e011L & (r & 1));
        acc0 += s11 ? -pr[r] : pr[r];
    }
    float T[3];
    #pragma unroll
    for (int pb = 0; pb < 3; ++pb) {
        float t = 0.f;
        #pragma unroll
        for (int r = 0; r < R; ++r) t += ((r >> pb) & 1) ? -pr[r] : pr[r];
        T[pb] = t;
    }

    float contrib[NQ];
    contrib[0] = acc0;                                   // wire0 (bit11 ^ fold)
    #pragma unroll
    for (int q = 1; q < 9; ++q) contrib[q] = ((tid >> (8 - q)) & 1) ? -S : S;
    contrib[9] = T[2]; contrib[10] = T[1]; contrib[11] = T[0];

    // all-VALU wave reduction (DPP/permlane), phase-split per step
    #pragma unroll
    for (int step = 0; step < 6; ++step) {
        float o[NQ];
        #pragma unroll
        for (int q = 0; q < NQ; ++q) {
            switch (step) {
                case 0: o[q] = lanex< 1>(contrib[q], tid); break;
                case 1: o[q] = lanex< 2>(contrib[q], tid); break;
                case 2: o[q] = lanex< 4>(contrib[q], tid); break;
                case 3: o[q] = lanex< 8>(contrib[q], tid); break;
                case 4: o[q] = lanex<16>(contrib[q], tid); break;
                default: o[q] = lanex<32>(contrib[q], tid); break;
            }
        }
        #pragma unroll
        for (int q = 0; q < NQ; ++q) contrib[q] += o[q];
    }
    if ((tid & 63) == 0) {
        const int wv = tid >> 6;
        #pragma unroll
        for (int q = 0; q < NQ; ++q) redbuf[wv * NQ + q] = contrib[q];
    }
    __syncthreads();
    if (tid < NQ) {
        float s = 0.f;
        #pragma unroll
        for (int wv = 0; wv < 8; ++wv) s += redbuf[wv * NQ + tid];
        out[b * NQ + tid] = s;
    }
}

extern "C" void kernel_launch(void* const* d_in, const int* in_sizes, int n_in,
                              void* d_out, int out_size, void* d_ws, size_t ws_size,
                              hipStream_t stream) {
    const float* x   = (const float*)d_in[0];  // (B,12)
    const float* w   = (const float*)d_in[1];  // (4,12,3)
    const float* ent = (const float*)d_in[2];  // (4,12)
    float* out = (float*)d_out;
    const int B = in_sizes[0] / NQ;
    qsim_kernel<<<B, BLK, 0, stream>>>(x, w, ent, out);
}